// Round 8
// baseline (834.632 us; speedup 1.0000x reference)
//
#include <hip/hip_runtime.h>
#include <cstddef>

#define NN 50000
#define HH 128
#define TT 4
#define EE 150000

typedef __attribute__((ext_vector_type(8))) short bfrag8;
typedef __attribute__((ext_vector_type(4))) float f32x4;
typedef __attribute__((ext_vector_type(8))) unsigned short u16x8;

__device__ __forceinline__ float sigm(float v) { return 1.0f / (1.0f + __expf(-v)); }

__device__ __forceinline__ float gru_elem(float xr, float xz, float xn,
                                          float hr, float hz, float hn, float h) {
    float r = sigm(xr + hr);
    float z = sigm(xz + hz);
    float nn = tanhf(xn + r * hn);
    return (1.f - z) * nn + z * h;
}

__device__ __forceinline__ unsigned short f2b(float f) {
    unsigned int u = __float_as_uint(f);
    u += 0x7fffu + ((u >> 16) & 1u);
    return (unsigned short)(u >> 16);
}
__device__ __forceinline__ float b2f(unsigned short s) {
    return __uint_as_float(((unsigned int)s) << 16);
}

__device__ __forceinline__ void gload_lds16(const void* gp, void* lp) {
    __builtin_amdgcn_global_load_lds(
        (const __attribute__((address_space(1))) unsigned int*)gp,
        (__attribute__((address_space(3))) unsigned int*)lp, 16, 0, 0);
}

// ================= bucket CSR build (once per call) =================
// deg ~ Poisson(12): P(deg>64) ~ 1e-30 -> fixed stride-64 buckets are safe.
__global__ __launch_bounds__(256)
void place_bucket(const int* __restrict__ edges, int* __restrict__ cnt,
                  unsigned int* __restrict__ rows) {
    int eg = blockIdx.x * 256 + threadIdx.x;
    if (eg >= TT * EE) return;
    int t = eg / EE;
    int src = edges[eg * 2];
    int tgt = edges[eg * 2 + 1];
    int p = atomicAdd(&cnt[tgt], 1);
    if (p < 64) rows[tgt * 64 + p] = (unsigned int)src * 512u + (unsigned int)t * 128u;
}

// ================= fused setup converts =================
__device__ __forceinline__ int permrow(int f) {
    int gc = f & 127, ch = f >> 7;
    return (gc >> 4) * 48 + ch * 16 + (gc & 15);
}

__global__ __launch_bounds__(256)
void setup_convert(const float* __restrict__ msg_W,
                   const float* __restrict__ W0ih, const float* __restrict__ W0hh,
                   const float* __restrict__ W1ih, const float* __restrict__ W1hh,
                   const float* __restrict__ b0ih, const float* __restrict__ b0hh,
                   const float* __restrict__ b1ih, const float* __restrict__ b1hh,
                   const float* __restrict__ x,
                   unsigned short* __restrict__ msgWb,
                   unsigned short* __restrict__ W0ihP, unsigned short* __restrict__ W0hhP,
                   unsigned short* __restrict__ W1ihP, unsigned short* __restrict__ W1hhP,
                   float* __restrict__ biasP,
                   unsigned short* __restrict__ xb, unsigned short* __restrict__ hbA,
                   float* __restrict__ out) {
    int i = blockIdx.x * 256 + threadIdx.x;
    if (i < 131072) { msgWb[i] = f2b(msg_W[i]); return; }
    i -= 131072;
    if (i < 49152) { int f = i >> 7, k = i & 127; W0ihP[permrow(f) * 128 + k] = f2b(W0ih[i]); return; }
    i -= 49152;
    if (i < 49152) { int f = i >> 7, k = i & 127; W0hhP[permrow(f) * 128 + k] = f2b(W0hh[i]); return; }
    i -= 49152;
    if (i < 98304) { int f = i >> 8, k = i & 255; W1ihP[permrow(f) * 256 + k] = f2b(W1ih[i]); return; }
    i -= 98304;
    if (i < 49152) { int f = i >> 7, k = i & 127; W1hhP[permrow(f) * 128 + k] = f2b(W1hh[i]); return; }
    i -= 49152;
    if (i < 1536) {
        int which = i / 384, f = i - which * 384;
        const float* src = (which == 0) ? b0ih : (which == 1) ? b0hh : (which == 2) ? b1ih : b1hh;
        biasP[which * 384 + permrow(f)] = src[f];
        return;
    }
    i -= 1536;
    if (i < NN * HH) {
        float v = x[i];
        unsigned short b = f2b(v);
        xb[i] = b;
        hbA[i] = b;
        out[i] = v;
    }
}

// ================= gather: inc[n] = sum_edges Z[rows[p] + c] =================
// 64 lanes per node (one wave): 4 edge-subsets x 16 col-lanes; 2-level shuffle
// combine. grid exact NN*64/256.
__global__ __launch_bounds__(256)
void gather64(const int* __restrict__ cnt, const unsigned int* __restrict__ rows,
              const unsigned short* __restrict__ Z, unsigned short* __restrict__ incb) {
    int gid = blockIdx.x * 256 + threadIdx.x;
    int n = gid >> 6;
    int lane = gid & 63;
    int sub = lane >> 4;
    int c = (lane & 15) * 8;
    int m = cnt[n];
    if (m > 64) m = 64;
    const unsigned int* rp = rows + n * 64;
    float a[8] = {};
    int p = sub;
    for (; p + 4 < m; p += 8) {
        unsigned int o0 = rp[p], o1 = rp[p + 4];
        u16x8 v0 = *(const u16x8*)&Z[o0 + c];
        u16x8 v1 = *(const u16x8*)&Z[o1 + c];
        #pragma unroll
        for (int j = 0; j < 8; ++j)
            a[j] += b2f((unsigned short)v0[j]) + b2f((unsigned short)v1[j]);
    }
    for (; p < m; p += 4) {
        u16x8 v = *(const u16x8*)&Z[rp[p] + c];
        #pragma unroll
        for (int j = 0; j < 8; ++j) a[j] += b2f((unsigned short)v[j]);
    }
    #pragma unroll
    for (int j = 0; j < 8; ++j) a[j] += __shfl_xor(a[j], 16, 64);
    #pragma unroll
    for (int j = 0; j < 8; ++j) a[j] += __shfl_xor(a[j], 32, 64);
    if (sub == 0) {
        u16x8 o;
        #pragma unroll
        for (int j = 0; j < 8; ++j) o[j] = f2b(a[j]);
        *(u16x8*)&incb[(size_t)n * 128 + c] = o;
    }
}

// ================= Z GEMM: Z = h @ msgW^T + msg_b (128x128 tile) =================
__global__ __launch_bounds__(256)
void z_gemm(const unsigned short* __restrict__ A0,
            const unsigned short* __restrict__ B,
            const float* __restrict__ bias,
            unsigned short* __restrict__ C) {
    __shared__ unsigned short lsA[128 * 64];
    __shared__ unsigned short lsB[128 * 64];
    const int tid = threadIdx.x;
    const int lane = tid & 63;
    const int w = tid >> 6;
    const int wm = w >> 1, wn = w & 1;
    const int ln15 = lane & 15;
    const int quad = lane >> 4;
    const int swz = ln15 & 7;
    const int mbase = blockIdx.x * 128;
    const int fbase = blockIdx.y * 128;
    const int qg = (lane & 7) ^ (lane >> 3);

    f32x4 acc[4][4];
    #pragma unroll
    for (int i = 0; i < 4; ++i)
        #pragma unroll
        for (int j = 0; j < 4; ++j)
            acc[i][j] = (f32x4){0.f, 0.f, 0.f, 0.f};

    #pragma unroll
    for (int tile = 0; tile < 2; ++tile) {
        const int ck0 = tile << 3;
        #pragma unroll
        for (int i = 0; i < 4; ++i) {
            const int r = i * 32 + (w << 3) + (lane >> 3);
            const int chunk = ck0 + qg;
            int grow = mbase + r;
            if (grow > NN - 1) grow = NN - 1;
            const int kel = chunk << 3;
            gload_lds16(A0 + (size_t)grow * 128 + kel, &lsA[(i * 32 + (w << 3)) * 64]);
            gload_lds16(B + (size_t)(fbase + r) * 128 + kel, &lsB[(i * 32 + (w << 3)) * 64]);
        }
        __syncthreads();
        #pragma unroll
        for (int kk = 0; kk < 2; ++kk) {
            const int cs = (((kk * 4 + quad) ^ swz)) << 3;
            bfrag8 aF[4], bF[4];
            #pragma unroll
            for (int mt = 0; mt < 4; ++mt)
                aF[mt] = *(const bfrag8*)&lsA[(wm * 64 + mt * 16 + ln15) * 64 + cs];
            #pragma unroll
            for (int nt = 0; nt < 4; ++nt)
                bF[nt] = *(const bfrag8*)&lsB[(wn * 64 + nt * 16 + ln15) * 64 + cs];
            #pragma unroll
            for (int mt = 0; mt < 4; ++mt)
                #pragma unroll
                for (int nt = 0; nt < 4; ++nt)
                    acc[mt][nt] = __builtin_amdgcn_mfma_f32_16x16x32_bf16(
                        aF[mt], bF[nt], acc[mt][nt], 0, 0, 0);
        }
        __syncthreads();
    }

    float bcol[4];
    #pragma unroll
    for (int nt = 0; nt < 4; ++nt)
        bcol[nt] = bias[fbase + wn * 64 + nt * 16 + ln15];
    #pragma unroll
    for (int mt = 0; mt < 4; ++mt) {
        #pragma unroll
        for (int reg = 0; reg < 4; ++reg) {
            const int grow = mbase + wm * 64 + mt * 16 + quad * 4 + reg;
            if (grow < NN) {
                #pragma unroll
                for (int nt = 0; nt < 4; ++nt) {
                    const int gcol = fbase + wn * 64 + nt * 16 + ln15;
                    C[(size_t)grow * 512 + gcol] = f2b(acc[mt][nt][reg] + bcol[nt]);
                }
            }
        }
    }
}

// ========== generic gx GEMM: C = [A0|A1] @ B^T + bias (B LDS-staged) ==========
__global__ __launch_bounds__(256)
void mfma_gemm(const unsigned short* __restrict__ A0,
               const unsigned short* __restrict__ A1, int K0, int K,
               const unsigned short* __restrict__ B,
               const float* __restrict__ bias,
               unsigned short* __restrict__ C, int ldc, int M) {
    __shared__ unsigned short lsA[128 * 64];
    __shared__ unsigned short lsB[128 * 64];
    const int tid = threadIdx.x;
    const int lane = tid & 63;
    const int w = tid >> 6;
    const int wm = w >> 1, wn = w & 1;
    const int ln15 = lane & 15;
    const int quad = lane >> 4;
    const int swz = ln15 & 7;
    const int mbase = blockIdx.x * 128;
    const int fbase = blockIdx.y * 128;
    const int qg = (lane & 7) ^ (lane >> 3);

    f32x4 acc[4][4];
    #pragma unroll
    for (int i = 0; i < 4; ++i)
        #pragma unroll
        for (int j = 0; j < 4; ++j)
            acc[i][j] = (f32x4){0.f, 0.f, 0.f, 0.f};

    const int ntiles = K >> 6;
    for (int tile = 0; tile < ntiles; ++tile) {
        const int ck0 = tile << 3;
        #pragma unroll
        for (int i = 0; i < 4; ++i) {
            const int r = i * 32 + (w << 3) + (lane >> 3);
            const int chunk = ck0 + qg;
            int grow = mbase + r;
            if (grow > M - 1) grow = M - 1;
            const int kel = chunk << 3;
            const unsigned short* gpA =
                (kel < K0) ? (A0 + (size_t)grow * K0 + kel)
                           : (A1 + (size_t)grow * (K - K0) + (kel - K0));
            gload_lds16(gpA, &lsA[(i * 32 + (w << 3)) * 64]);
            gload_lds16(B + (size_t)(fbase + r) * K + kel, &lsB[(i * 32 + (w << 3)) * 64]);
        }
        __syncthreads();
        #pragma unroll
        for (int kk = 0; kk < 2; ++kk) {
            const int cs = (((kk * 4 + quad) ^ swz)) << 3;
            bfrag8 aF[4], bF[4];
            #pragma unroll
            for (int mt = 0; mt < 4; ++mt)
                aF[mt] = *(const bfrag8*)&lsA[(wm * 64 + mt * 16 + ln15) * 64 + cs];
            #pragma unroll
            for (int nt = 0; nt < 4; ++nt)
                bF[nt] = *(const bfrag8*)&lsB[(wn * 64 + nt * 16 + ln15) * 64 + cs];
            #pragma unroll
            for (int mt = 0; mt < 4; ++mt)
                #pragma unroll
                for (int nt = 0; nt < 4; ++nt)
                    acc[mt][nt] = __builtin_amdgcn_mfma_f32_16x16x32_bf16(
                        aF[mt], bF[nt], acc[mt][nt], 0, 0, 0);
        }
        __syncthreads();
    }

    float bcol[4];
    #pragma unroll
    for (int nt = 0; nt < 4; ++nt)
        bcol[nt] = bias[fbase + wn * 64 + nt * 16 + ln15];
    #pragma unroll
    for (int mt = 0; mt < 4; ++mt) {
        #pragma unroll
        for (int reg = 0; reg < 4; ++reg) {
            const int grow = mbase + wm * 64 + mt * 16 + quad * 4 + reg;
            if (grow < M) {
                #pragma unroll
                for (int nt = 0; nt < 4; ++nt) {
                    const int gcol = fbase + wn * 64 + nt * 16 + ln15;
                    C[(size_t)grow * ldc + gcol] = f2b(acc[mt][nt][reg] + bcol[nt]);
                }
            }
        }
    }
}

// ============ fused gh-GEMM + GRU gate (512 thr, M-tile 128, B LDS-staged) ============
__global__ __launch_bounds__(512)
void ghgate_kernel(const unsigned short* __restrict__ hb,
                   const unsigned short* __restrict__ Wp,
                   const float* __restrict__ bp,
                   const unsigned short* __restrict__ gx,
                   const float* __restrict__ hcur,
                   float* __restrict__ hnext, unsigned short* __restrict__ hbn,
                   int M) {
    __shared__ unsigned short lsA[128 * 64];   // 16 KB
    __shared__ unsigned short lsB[384 * 64];   // 48 KB
    const int tid = threadIdx.x;
    const int lane = tid & 63;
    const int w = tid >> 6;             // 0..7
    const int ln15 = lane & 15;
    const int quad = lane >> 4;
    const int swz = ln15 & 7;
    const int mbase = blockIdx.x * 128;
    const int srow = tid >> 3;          // staging row 0..63
    const int slot = tid & 7;

    f32x4 acc[8][3];
    #pragma unroll
    for (int i = 0; i < 8; ++i)
        #pragma unroll
        for (int j = 0; j < 3; ++j)
            acc[i][j] = (f32x4){0.f, 0.f, 0.f, 0.f};

    #pragma unroll
    for (int tile = 0; tile < 2; ++tile) {
        const int ck0 = tile << 3;
        // stage A: 128x64 panel (two 64-row halves)
        #pragma unroll
        for (int hhf = 0; hhf < 2; ++hhf) {
            int r = hhf * 64 + srow;
            int grow = mbase + r;
            if (grow > M - 1) grow = M - 1;
            const int chunk = ck0 + (slot ^ (srow & 7));
            gload_lds16(hb + (size_t)grow * 128 + (chunk << 3),
                        &lsA[(hhf * 512 + tid) * 8]);
        }
        // stage B: 6 panels of 64x64
        #pragma unroll
        for (int pi = 0; pi < 6; ++pi) {
            const int brow = pi * 64 + srow;
            const int chunk = ck0 + (slot ^ (srow & 7));
            gload_lds16(Wp + (size_t)brow * 128 + (chunk << 3),
                        &lsB[(pi * 512 + tid) * 8]);
        }
        __syncthreads();
        #pragma unroll
        for (int kk = 0; kk < 2; ++kk) {
            const int cs = ((kk * 4 + quad) ^ swz) << 3;
            bfrag8 aF[8], bF[3];
            #pragma unroll
            for (int mt = 0; mt < 8; ++mt)
                aF[mt] = *(const bfrag8*)&lsA[(mt * 16 + ln15) * 64 + cs];
            #pragma unroll
            for (int nt = 0; nt < 3; ++nt) {
                const int rb = w * 48 + nt * 16 + ln15;
                bF[nt] = *(const bfrag8*)&lsB[rb * 64 + cs];
            }
            #pragma unroll
            for (int mt = 0; mt < 8; ++mt)
                #pragma unroll
                for (int nt = 0; nt < 3; ++nt)
                    acc[mt][nt] = __builtin_amdgcn_mfma_f32_16x16x32_bf16(
                        aF[mt], bF[nt], acc[mt][nt], 0, 0, 0);
        }
        __syncthreads();
    }

    const float br = bp[w * 48 + ln15];
    const float bz = bp[w * 48 + 16 + ln15];
    const float bn = bp[w * 48 + 32 + ln15];
    const int gc = w * 16 + ln15;
    #pragma unroll
    for (int mt = 0; mt < 8; ++mt) {
        #pragma unroll
        for (int reg = 0; reg < 4; ++reg) {
            const int row = mbase + mt * 16 + quad * 4 + reg;
            if (row < M) {
                const size_t gb = (size_t)row * 384 + w * 48;
                const float xr = b2f(gx[gb + ln15]);
                const float xz = b2f(gx[gb + 16 + ln15]);
                const float xn = b2f(gx[gb + 32 + ln15]);
                const float hrv = acc[mt][0][reg] + br;
                const float hzv = acc[mt][1][reg] + bz;
                const float hnv = acc[mt][2][reg] + bn;
                const float h = hcur[(size_t)row * 128 + gc];
                const float o = gru_elem(xr, xz, xn, hrv, hzv, hnv, h);
                hnext[(size_t)row * 128 + gc] = o;
                hbn[(size_t)row * 128 + gc] = f2b(o);
            }
        }
    }
}

extern "C" void kernel_launch(void* const* d_in, const int* in_sizes, int n_in,
                              void* d_out, int out_size, void* d_ws, size_t ws_size,
                              hipStream_t stream) {
    (void)in_sizes; (void)n_in; (void)out_size; (void)ws_size;
    const float* x     = (const float*)d_in[0];
    const int*   edges = (const int*)d_in[1];
    const float* msg_W = (const float*)d_in[2];
    const float* msg_b = (const float*)d_in[3];
    const float* W0ih  = (const float*)d_in[4];
    const float* W0hh  = (const float*)d_in[5];
    const float* b0ih  = (const float*)d_in[6];
    const float* b0hh  = (const float*)d_in[7];
    const float* W1ih  = (const float*)d_in[8];
    const float* W1hh  = (const float*)d_in[9];
    const float* b1ih  = (const float*)d_in[10];
    const float* b1hh  = (const float*)d_in[11];
    float* out = (float*)d_out;

    // ---- workspace layout (float units) ----
    float* ws = (float*)d_ws;
    unsigned short* Zb   = (unsigned short*)ws;                  // N*512 u16 = 12.8M fl
    unsigned short* gxb  = (unsigned short*)(ws + 12800000);     // N*384 u16 =  9.6M fl
    unsigned short* incb = (unsigned short*)(ws + 22400000);     // N*128 u16
    unsigned short* xb   = (unsigned short*)(ws + 25600000);     // N*128
    unsigned short* hbA  = (unsigned short*)(ws + 28800000);
    unsigned short* hbB  = (unsigned short*)(ws + 32000000);
    float* hA            = ws + 35200000;                        // N*128 fp32
    unsigned short* wb   = (unsigned short*)(ws + 41600000);
    unsigned short* msgWb = wb;               // 131072 u16
    unsigned short* W0ihP = wb + 131072;      // 49152
    unsigned short* W0hhP = wb + 180224;      // 49152
    unsigned short* W1ihP = wb + 229376;      // 98304
    unsigned short* W1hhP = wb + 327680;      // 49152
    float* biasP        = ws + 41800000;                         // 1536 fl
    int*          cnt   = (int*)(ws + 41900000);                 // NN ints
    unsigned int* rows  = (unsigned int*)(ws + 42000000);        // NN*64 u32 = 3.2M fl

    // ---- bucket CSR build (2 dispatches) ----
    hipMemsetAsync(cnt, 0, (size_t)NN * sizeof(int), stream);
    place_bucket<<<(TT * EE + 255) / 256, 256, 0, stream>>>(edges, cnt, rows);

    // ---- fused converts (also writes out = x as fp32 h0) ----
    setup_convert<<<26478, 256, 0, stream>>>(msg_W, W0ih, W0hh, W1ih, W1hh,
                                             b0ih, b0hh, b1ih, b1hh, x,
                                             msgWb, W0ihP, W0hhP, W1ihP, W1hhP,
                                             biasP, xb, hbA, out);

    const int mblocks = (NN + 127) / 128;   // 391
    for (int s = 0; s < 6; ++s) {
        const int l = s / 3;
        const float* hcur  = (s % 2 == 0) ? out : hA;
        float*       hnext = (s % 2 == 0) ? hA : out;
        unsigned short* hbc = (s % 2 == 0) ? hbA : hbB;
        unsigned short* hbn = (s % 2 == 0) ? hbB : hbA;

        z_gemm<<<dim3(mblocks, 4), 256, 0, stream>>>(
            hbc, msgWb + (size_t)l * 65536, msg_b + (size_t)l * 512, Zb);
        gather64<<<(NN * 64) / 256, 256, 0, stream>>>(cnt, rows, Zb, incb);
        if (l == 0) {
            mfma_gemm<<<dim3(mblocks, 3), 256, 0, stream>>>(
                incb, incb, 128, 128, W0ihP, biasP, gxb, 384, NN);
            ghgate_kernel<<<mblocks, 512, 0, stream>>>(
                hbc, W0hhP, biasP + 384, gxb, hcur, hnext, hbn, NN);
        } else {
            mfma_gemm<<<dim3(mblocks, 3), 256, 0, stream>>>(
                xb, incb, 128, 256, W1ihP, biasP + 768, gxb, 384, NN);
            ghgate_kernel<<<mblocks, 512, 0, stream>>>(
                hbc, W1hhP, biasP + 1152, gxb, hcur, hnext, hbn, NN);
        }
    }
    // s=5 (odd) writes hnext=out — final h lands in d_out.
}

// Round 9
// 752.333 us; speedup vs baseline: 1.1094x; 1.1094x over previous
//
#include <hip/hip_runtime.h>
#include <cstddef>

#define NN 50000
#define HH 128
#define TT 4
#define EE 150000

typedef __attribute__((ext_vector_type(8))) short bfrag8;
typedef __attribute__((ext_vector_type(4))) float f32x4;
typedef __attribute__((ext_vector_type(8))) unsigned short u16x8;

__device__ __forceinline__ float sigm(float v) { return 1.0f / (1.0f + __expf(-v)); }

__device__ __forceinline__ float gru_elem(float xr, float xz, float xn,
                                          float hr, float hz, float hn, float h) {
    float r = sigm(xr + hr);
    float z = sigm(xz + hz);
    float nn = tanhf(xn + r * hn);
    return (1.f - z) * nn + z * h;
}

__device__ __forceinline__ unsigned short f2b(float f) {
    unsigned int u = __float_as_uint(f);
    u += 0x7fffu + ((u >> 16) & 1u);
    return (unsigned short)(u >> 16);
}
__device__ __forceinline__ float b2f(unsigned short s) {
    return __uint_as_float(((unsigned int)s) << 16);
}

__device__ __forceinline__ void gload_lds16(const void* gp, void* lp) {
    __builtin_amdgcn_global_load_lds(
        (const __attribute__((address_space(1))) unsigned int*)gp,
        (__attribute__((address_space(3))) unsigned int*)lp, 16, 0, 0);
}

// ================= bucket CSR build (once per call) =================
// deg ~ Poisson(12): P(deg>64) ~ 1e-30 -> fixed stride-64 buckets are safe.
__global__ __launch_bounds__(256)
void place_bucket(const int* __restrict__ edges, int* __restrict__ cnt,
                  unsigned int* __restrict__ rows) {
    int eg = blockIdx.x * 256 + threadIdx.x;
    if (eg >= TT * EE) return;
    int t = eg / EE;
    int src = edges[eg * 2];
    int tgt = edges[eg * 2 + 1];
    int p = atomicAdd(&cnt[tgt], 1);
    if (p < 64) rows[tgt * 64 + p] = (unsigned int)src * 512u + (unsigned int)t * 128u;
}

// ================= fused setup converts =================
__device__ __forceinline__ int permrow(int f) {
    int gc = f & 127, ch = f >> 7;
    return (gc >> 4) * 48 + ch * 16 + (gc & 15);
}

__global__ __launch_bounds__(256)
void setup_convert(const float* __restrict__ msg_W,
                   const float* __restrict__ W0ih, const float* __restrict__ W0hh,
                   const float* __restrict__ W1ih, const float* __restrict__ W1hh,
                   const float* __restrict__ b0ih, const float* __restrict__ b0hh,
                   const float* __restrict__ b1ih, const float* __restrict__ b1hh,
                   const float* __restrict__ x,
                   unsigned short* __restrict__ msgWb,
                   unsigned short* __restrict__ W0ihP, unsigned short* __restrict__ W0hhP,
                   unsigned short* __restrict__ W1ihP, unsigned short* __restrict__ W1hhP,
                   float* __restrict__ biasP,
                   unsigned short* __restrict__ xb, unsigned short* __restrict__ hbA,
                   float* __restrict__ out) {
    int i = blockIdx.x * 256 + threadIdx.x;
    if (i < 131072) { msgWb[i] = f2b(msg_W[i]); return; }
    i -= 131072;
    if (i < 49152) { int f = i >> 7, k = i & 127; W0ihP[permrow(f) * 128 + k] = f2b(W0ih[i]); return; }
    i -= 49152;
    if (i < 49152) { int f = i >> 7, k = i & 127; W0hhP[permrow(f) * 128 + k] = f2b(W0hh[i]); return; }
    i -= 49152;
    if (i < 98304) { int f = i >> 8, k = i & 255; W1ihP[permrow(f) * 256 + k] = f2b(W1ih[i]); return; }
    i -= 98304;
    if (i < 49152) { int f = i >> 7, k = i & 127; W1hhP[permrow(f) * 128 + k] = f2b(W1hh[i]); return; }
    i -= 49152;
    if (i < 1536) {
        int which = i / 384, f = i - which * 384;
        const float* src = (which == 0) ? b0ih : (which == 1) ? b0hh : (which == 2) ? b1ih : b1hh;
        biasP[which * 384 + permrow(f)] = src[f];
        return;
    }
    i -= 1536;
    if (i < NN * HH) {
        float v = x[i];
        unsigned short b = f2b(v);
        xb[i] = b;
        hbA[i] = b;
        out[i] = v;
    }
}

// ================= gather: inc[n] = sum_edges Z[rows[p] + c] =================
// 64 lanes per node (one wave): 4 edge-subsets x 16 col-lanes; 2-level shuffle
// combine. grid exact NN*64/256.
__global__ __launch_bounds__(256)
void gather64(const int* __restrict__ cnt, const unsigned int* __restrict__ rows,
              const unsigned short* __restrict__ Z, unsigned short* __restrict__ incb) {
    int gid = blockIdx.x * 256 + threadIdx.x;
    int n = gid >> 6;
    int lane = gid & 63;
    int sub = lane >> 4;
    int c = (lane & 15) * 8;
    int m = cnt[n];
    if (m > 64) m = 64;
    const unsigned int* rp = rows + n * 64;
    float a[8] = {};
    int p = sub;
    for (; p + 4 < m; p += 8) {
        unsigned int o0 = rp[p], o1 = rp[p + 4];
        u16x8 v0 = *(const u16x8*)&Z[o0 + c];
        u16x8 v1 = *(const u16x8*)&Z[o1 + c];
        #pragma unroll
        for (int j = 0; j < 8; ++j)
            a[j] += b2f((unsigned short)v0[j]) + b2f((unsigned short)v1[j]);
    }
    for (; p < m; p += 4) {
        u16x8 v = *(const u16x8*)&Z[rp[p] + c];
        #pragma unroll
        for (int j = 0; j < 8; ++j) a[j] += b2f((unsigned short)v[j]);
    }
    #pragma unroll
    for (int j = 0; j < 8; ++j) a[j] += __shfl_xor(a[j], 16, 64);
    #pragma unroll
    for (int j = 0; j < 8; ++j) a[j] += __shfl_xor(a[j], 32, 64);
    if (sub == 0) {
        u16x8 o;
        #pragma unroll
        for (int j = 0; j < 8; ++j) o[j] = f2b(a[j]);
        *(u16x8*)&incb[(size_t)n * 128 + c] = o;
    }
}

// ================= Z GEMM: Z = h @ msgW^T + msg_b (128x128 tile) =================
__global__ __launch_bounds__(256)
void z_gemm(const unsigned short* __restrict__ A0,
            const unsigned short* __restrict__ B,
            const float* __restrict__ bias,
            unsigned short* __restrict__ C) {
    __shared__ unsigned short lsA[128 * 64];
    __shared__ unsigned short lsB[128 * 64];
    const int tid = threadIdx.x;
    const int lane = tid & 63;
    const int w = tid >> 6;
    const int wm = w >> 1, wn = w & 1;
    const int ln15 = lane & 15;
    const int quad = lane >> 4;
    const int swz = ln15 & 7;
    const int mbase = blockIdx.x * 128;
    const int fbase = blockIdx.y * 128;
    const int qg = (lane & 7) ^ (lane >> 3);

    f32x4 acc[4][4];
    #pragma unroll
    for (int i = 0; i < 4; ++i)
        #pragma unroll
        for (int j = 0; j < 4; ++j)
            acc[i][j] = (f32x4){0.f, 0.f, 0.f, 0.f};

    #pragma unroll
    for (int tile = 0; tile < 2; ++tile) {
        const int ck0 = tile << 3;
        #pragma unroll
        for (int i = 0; i < 4; ++i) {
            const int r = i * 32 + (w << 3) + (lane >> 3);
            const int chunk = ck0 + qg;
            int grow = mbase + r;
            if (grow > NN - 1) grow = NN - 1;
            const int kel = chunk << 3;
            gload_lds16(A0 + (size_t)grow * 128 + kel, &lsA[(i * 32 + (w << 3)) * 64]);
            gload_lds16(B + (size_t)(fbase + r) * 128 + kel, &lsB[(i * 32 + (w << 3)) * 64]);
        }
        __syncthreads();
        #pragma unroll
        for (int kk = 0; kk < 2; ++kk) {
            const int cs = (((kk * 4 + quad) ^ swz)) << 3;
            bfrag8 aF[4], bF[4];
            #pragma unroll
            for (int mt = 0; mt < 4; ++mt)
                aF[mt] = *(const bfrag8*)&lsA[(wm * 64 + mt * 16 + ln15) * 64 + cs];
            #pragma unroll
            for (int nt = 0; nt < 4; ++nt)
                bF[nt] = *(const bfrag8*)&lsB[(wn * 64 + nt * 16 + ln15) * 64 + cs];
            #pragma unroll
            for (int mt = 0; mt < 4; ++mt)
                #pragma unroll
                for (int nt = 0; nt < 4; ++nt)
                    acc[mt][nt] = __builtin_amdgcn_mfma_f32_16x16x32_bf16(
                        aF[mt], bF[nt], acc[mt][nt], 0, 0, 0);
        }
        __syncthreads();
    }

    float bcol[4];
    #pragma unroll
    for (int nt = 0; nt < 4; ++nt)
        bcol[nt] = bias[fbase + wn * 64 + nt * 16 + ln15];
    #pragma unroll
    for (int mt = 0; mt < 4; ++mt) {
        #pragma unroll
        for (int reg = 0; reg < 4; ++reg) {
            const int grow = mbase + wm * 64 + mt * 16 + quad * 4 + reg;
            if (grow < NN) {
                #pragma unroll
                for (int nt = 0; nt < 4; ++nt) {
                    const int gcol = fbase + wn * 64 + nt * 16 + ln15;
                    C[(size_t)grow * 512 + gcol] = f2b(acc[mt][nt][reg] + bcol[nt]);
                }
            }
        }
    }
}

// ========== generic gx GEMM: C = [A0|A1] @ B^T + bias (B LDS-staged) ==========
__global__ __launch_bounds__(256)
void mfma_gemm(const unsigned short* __restrict__ A0,
               const unsigned short* __restrict__ A1, int K0, int K,
               const unsigned short* __restrict__ B,
               const float* __restrict__ bias,
               unsigned short* __restrict__ C, int ldc, int M) {
    __shared__ unsigned short lsA[128 * 64];
    __shared__ unsigned short lsB[128 * 64];
    const int tid = threadIdx.x;
    const int lane = tid & 63;
    const int w = tid >> 6;
    const int wm = w >> 1, wn = w & 1;
    const int ln15 = lane & 15;
    const int quad = lane >> 4;
    const int swz = ln15 & 7;
    const int mbase = blockIdx.x * 128;
    const int fbase = blockIdx.y * 128;
    const int qg = (lane & 7) ^ (lane >> 3);

    f32x4 acc[4][4];
    #pragma unroll
    for (int i = 0; i < 4; ++i)
        #pragma unroll
        for (int j = 0; j < 4; ++j)
            acc[i][j] = (f32x4){0.f, 0.f, 0.f, 0.f};

    const int ntiles = K >> 6;
    for (int tile = 0; tile < ntiles; ++tile) {
        const int ck0 = tile << 3;
        #pragma unroll
        for (int i = 0; i < 4; ++i) {
            const int r = i * 32 + (w << 3) + (lane >> 3);
            const int chunk = ck0 + qg;
            int grow = mbase + r;
            if (grow > M - 1) grow = M - 1;
            const int kel = chunk << 3;
            const unsigned short* gpA =
                (kel < K0) ? (A0 + (size_t)grow * K0 + kel)
                           : (A1 + (size_t)grow * (K - K0) + (kel - K0));
            gload_lds16(gpA, &lsA[(i * 32 + (w << 3)) * 64]);
            gload_lds16(B + (size_t)(fbase + r) * K + kel, &lsB[(i * 32 + (w << 3)) * 64]);
        }
        __syncthreads();
        #pragma unroll
        for (int kk = 0; kk < 2; ++kk) {
            const int cs = (((kk * 4 + quad) ^ swz)) << 3;
            bfrag8 aF[4], bF[4];
            #pragma unroll
            for (int mt = 0; mt < 4; ++mt)
                aF[mt] = *(const bfrag8*)&lsA[(wm * 64 + mt * 16 + ln15) * 64 + cs];
            #pragma unroll
            for (int nt = 0; nt < 4; ++nt)
                bF[nt] = *(const bfrag8*)&lsB[(wn * 64 + nt * 16 + ln15) * 64 + cs];
            #pragma unroll
            for (int mt = 0; mt < 4; ++mt)
                #pragma unroll
                for (int nt = 0; nt < 4; ++nt)
                    acc[mt][nt] = __builtin_amdgcn_mfma_f32_16x16x32_bf16(
                        aF[mt], bF[nt], acc[mt][nt], 0, 0, 0);
        }
        __syncthreads();
    }

    float bcol[4];
    #pragma unroll
    for (int nt = 0; nt < 4; ++nt)
        bcol[nt] = bias[fbase + wn * 64 + nt * 16 + ln15];
    #pragma unroll
    for (int mt = 0; mt < 4; ++mt) {
        #pragma unroll
        for (int reg = 0; reg < 4; ++reg) {
            const int grow = mbase + wm * 64 + mt * 16 + quad * 4 + reg;
            if (grow < M) {
                #pragma unroll
                for (int nt = 0; nt < 4; ++nt) {
                    const int gcol = fbase + wn * 64 + nt * 16 + ln15;
                    C[(size_t)grow * ldc + gcol] = f2b(acc[mt][nt][reg] + bcol[nt]);
                }
            }
        }
    }
}

// ============ fused gh-GEMM + GRU gate (512 thr, M-tile 64, B LDS-staged) ============
__global__ __launch_bounds__(512)
void ghgate_kernel(const unsigned short* __restrict__ hb,
                   const unsigned short* __restrict__ Wp,
                   const float* __restrict__ bp,
                   const unsigned short* __restrict__ gx,
                   const float* __restrict__ hcur,
                   float* __restrict__ hnext, unsigned short* __restrict__ hbn,
                   int M) {
    __shared__ unsigned short lsA[64 * 64];    // 8 KB
    __shared__ unsigned short lsB[384 * 64];   // 48 KB
    const int tid = threadIdx.x;
    const int lane = tid & 63;
    const int w = tid >> 6;             // 0..7
    const int ln15 = lane & 15;
    const int quad = lane >> 4;
    const int swz = ln15 & 7;
    const int mbase = blockIdx.x * 64;
    const int srow = tid >> 3;          // staging row 0..63
    const int slot = tid & 7;

    f32x4 acc[4][3];
    #pragma unroll
    for (int i = 0; i < 4; ++i)
        #pragma unroll
        for (int j = 0; j < 3; ++j)
            acc[i][j] = (f32x4){0.f, 0.f, 0.f, 0.f};

    #pragma unroll
    for (int tile = 0; tile < 2; ++tile) {
        const int ck0 = tile << 3;
        {
            int grow = mbase + srow;
            if (grow > M - 1) grow = M - 1;
            const int chunk = ck0 + (slot ^ (srow & 7));
            gload_lds16(hb + (size_t)grow * 128 + (chunk << 3), &lsA[tid * 8]);
        }
        #pragma unroll
        for (int pi = 0; pi < 6; ++pi) {
            const int brow = pi * 64 + srow;
            const int chunk = ck0 + (slot ^ (srow & 7));
            gload_lds16(Wp + (size_t)brow * 128 + (chunk << 3),
                        &lsB[(pi * 512 + tid) * 8]);
        }
        __syncthreads();
        #pragma unroll
        for (int kk = 0; kk < 2; ++kk) {
            const int cs = ((kk * 4 + quad) ^ swz) << 3;
            bfrag8 aF[4], bF[3];
            #pragma unroll
            for (int mt = 0; mt < 4; ++mt)
                aF[mt] = *(const bfrag8*)&lsA[(mt * 16 + ln15) * 64 + cs];
            #pragma unroll
            for (int nt = 0; nt < 3; ++nt) {
                const int rb = w * 48 + nt * 16 + ln15;
                bF[nt] = *(const bfrag8*)&lsB[rb * 64 + cs];
            }
            #pragma unroll
            for (int mt = 0; mt < 4; ++mt)
                #pragma unroll
                for (int nt = 0; nt < 3; ++nt)
                    acc[mt][nt] = __builtin_amdgcn_mfma_f32_16x16x32_bf16(
                        aF[mt], bF[nt], acc[mt][nt], 0, 0, 0);
        }
        __syncthreads();
    }

    const float br = bp[w * 48 + ln15];
    const float bz = bp[w * 48 + 16 + ln15];
    const float bn = bp[w * 48 + 32 + ln15];
    const int gc = w * 16 + ln15;
    #pragma unroll
    for (int mt = 0; mt < 4; ++mt) {
        #pragma unroll
        for (int reg = 0; reg < 4; ++reg) {
            const int row = mbase + mt * 16 + quad * 4 + reg;
            if (row < M) {
                const size_t gb = (size_t)row * 384 + w * 48;
                const float xr = b2f(gx[gb + ln15]);
                const float xz = b2f(gx[gb + 16 + ln15]);
                const float xn = b2f(gx[gb + 32 + ln15]);
                const float hrv = acc[mt][0][reg] + br;
                const float hzv = acc[mt][1][reg] + bz;
                const float hnv = acc[mt][2][reg] + bn;
                const float h = hcur[(size_t)row * 128 + gc];
                const float o = gru_elem(xr, xz, xn, hrv, hzv, hnv, h);
                hnext[(size_t)row * 128 + gc] = o;
                hbn[(size_t)row * 128 + gc] = f2b(o);
            }
        }
    }
}

extern "C" void kernel_launch(void* const* d_in, const int* in_sizes, int n_in,
                              void* d_out, int out_size, void* d_ws, size_t ws_size,
                              hipStream_t stream) {
    (void)in_sizes; (void)n_in; (void)out_size; (void)ws_size;
    const float* x     = (const float*)d_in[0];
    const int*   edges = (const int*)d_in[1];
    const float* msg_W = (const float*)d_in[2];
    const float* msg_b = (const float*)d_in[3];
    const float* W0ih  = (const float*)d_in[4];
    const float* W0hh  = (const float*)d_in[5];
    const float* b0ih  = (const float*)d_in[6];
    const float* b0hh  = (const float*)d_in[7];
    const float* W1ih  = (const float*)d_in[8];
    const float* W1hh  = (const float*)d_in[9];
    const float* b1ih  = (const float*)d_in[10];
    const float* b1hh  = (const float*)d_in[11];
    float* out = (float*)d_out;

    // ---- workspace layout (float units) ----
    float* ws = (float*)d_ws;
    unsigned short* Zb   = (unsigned short*)ws;                  // N*512 u16 = 12.8M fl
    unsigned short* gxb  = (unsigned short*)(ws + 12800000);     // N*384 u16 =  9.6M fl
    unsigned short* incb = (unsigned short*)(ws + 22400000);     // N*128 u16
    unsigned short* xb   = (unsigned short*)(ws + 25600000);     // N*128
    unsigned short* hbA  = (unsigned short*)(ws + 28800000);
    unsigned short* hbB  = (unsigned short*)(ws + 32000000);
    float* hA            = ws + 35200000;                        // N*128 fp32
    unsigned short* wb   = (unsigned short*)(ws + 41600000);
    unsigned short* msgWb = wb;               // 131072 u16
    unsigned short* W0ihP = wb + 131072;      // 49152
    unsigned short* W0hhP = wb + 180224;      // 49152
    unsigned short* W1ihP = wb + 229376;      // 98304
    unsigned short* W1hhP = wb + 327680;      // 49152
    float* biasP        = ws + 41800000;                         // 1536 fl
    int*          cnt   = (int*)(ws + 41900000);                 // NN ints
    unsigned int* rows  = (unsigned int*)(ws + 42000000);        // NN*64 u32 = 3.2M fl

    // ---- bucket CSR build (2 dispatches) ----
    hipMemsetAsync(cnt, 0, (size_t)NN * sizeof(int), stream);
    place_bucket<<<(TT * EE + 255) / 256, 256, 0, stream>>>(edges, cnt, rows);

    // ---- fused converts (also writes out = x as fp32 h0) ----
    setup_convert<<<26478, 256, 0, stream>>>(msg_W, W0ih, W0hh, W1ih, W1hh,
                                             b0ih, b0hh, b1ih, b1hh, x,
                                             msgWb, W0ihP, W0hhP, W1ihP, W1hhP,
                                             biasP, xb, hbA, out);

    const int mblocks = (NN + 127) / 128;   // 391
    const int gblocks = (NN + 63) / 64;     // 782
    for (int s = 0; s < 6; ++s) {
        const int l = s / 3;
        const float* hcur  = (s % 2 == 0) ? out : hA;
        float*       hnext = (s % 2 == 0) ? hA : out;
        unsigned short* hbc = (s % 2 == 0) ? hbA : hbB;
        unsigned short* hbn = (s % 2 == 0) ? hbB : hbA;

        z_gemm<<<dim3(mblocks, 4), 256, 0, stream>>>(
            hbc, msgWb + (size_t)l * 65536, msg_b + (size_t)l * 512, Zb);
        gather64<<<(NN * 64) / 256, 256, 0, stream>>>(cnt, rows, Zb, incb);
        if (l == 0) {
            mfma_gemm<<<dim3(mblocks, 3), 256, 0, stream>>>(
                incb, incb, 128, 128, W0ihP, biasP, gxb, 384, NN);
            ghgate_kernel<<<gblocks, 512, 0, stream>>>(
                hbc, W0hhP, biasP + 384, gxb, hcur, hnext, hbn, NN);
        } else {
            mfma_gemm<<<dim3(mblocks, 3), 256, 0, stream>>>(
                xb, incb, 128, 256, W1ihP, biasP + 768, gxb, 384, NN);
            ghgate_kernel<<<gblocks, 512, 0, stream>>>(
                hbc, W1hhP, biasP + 1152, gxb, hcur, hnext, hbn, NN);
        }
    }
    // s=5 (odd) writes hnext=out — final h lands in d_out.
}